// Round 12
// baseline (8080.813 us; speedup 1.0000x reference)
//
#include <hip/hip_runtime.h>
#include <stdint.h>

#define NPTS 8192
#define NS   2048
#define KNNK 32

typedef unsigned long long u64;
typedef float f32x2 __attribute__((ext_vector_type(2)));

// ============================ FPS =============================
// R4's kernel VERBATIM — kept byte-identical as the within-run reference
// (cross-run clock variance is +-25-30%, so only same-run comparisons count).
__global__ __launch_bounds__(512)
void fps_kernel(const float* __restrict__ pts,
                float* __restrict__ out_xyz)
{
#pragma clang fp contract(off)
    const int bt  = blockIdx.x;        // b*4 + t0
    const int tid = threadIdx.x;
    const float* frame = pts + (size_t)bt * NPTS * 6;

    __shared__ float4 p4[NPTS];        // 128 KB coords copy
    __shared__ u64 ring[3];

    f32x2 x2[8], y2[8], z2[8], dd2[8];
#pragma unroll
    for (int j = 0; j < 16; ++j) {
        int n = j * 512 + tid;
        float x = frame[n*6+0], y = frame[n*6+1], z = frame[n*6+2];
        x2[j >> 1][j & 1] = x;
        y2[j >> 1][j & 1] = y;
        z2[j >> 1][j & 1] = z;
        dd2[j >> 1][j & 1] = 3.4028234663852886e38f;
        p4[n] = make_float4(x, y, z, 0.0f);
    }
    if (tid < 3) ring[tid] = 0;
    if (tid == 0) {                    // selection 0 = point 0
        float* ow = out_xyz + (size_t)bt * NS * 3;
        ow[0] = x2[0][0]; ow[1] = y2[0][0]; ow[2] = z2[0][0];
    }
    __syncthreads();
    float sx = p4[0].x, sy = p4[0].y, sz = p4[0].z;

    int r = 1;                         // ring slot for iteration i
    for (int i = 1; i < NS; ++i) {
        f32x2 sxv = {sx, sx}, syv = {sy, sy}, szv = {sz, sz};
        f32x2 m2 = {0.0f, 0.0f};
#pragma unroll
        for (int q = 0; q < 8; ++q) {
            f32x2 dx = x2[q] - sxv;
            f32x2 dy = y2[q] - syv;
            f32x2 dz = z2[q] - szv;
            f32x2 dd = (dx*dx + dy*dy) + dz*dz;
            f32x2 nd;
            nd[0] = fminf(dd2[q][0], dd[0]);
            nd[1] = fminf(dd2[q][1], dd[1]);
            dd2[q] = nd;
            m2[0] = fmaxf(m2[0], nd[0]);
            m2[1] = fmaxf(m2[1], nd[1]);
        }
        float mloc = fmaxf(m2[0], m2[1]);
        int bestn = 0;
#pragma unroll
        for (int j = 15; j >= 0; --j)
            bestn = (dd2[j >> 1][j & 1] == mloc) ? (j * 512 + tid) : bestn;
        u64 key = ((u64)__float_as_uint(mloc) << 32) | (unsigned)(8191 - bestn);
#pragma unroll
        for (int off = 32; off > 0; off >>= 1) {
            u64 o = __shfl_xor(key, off, 64);
            key = (o > key) ? o : key;
        }
        if ((tid & 63) == 0) atomicMax(&ring[r], key);
        int rn = r + 1; if (rn == 3) rn = 0;
        if (tid == 0) ring[rn] = 0;
        __syncthreads();
        u64 k = ring[r];
        int idx = 8191 - (int)(k & 0xFFFFFFFFu);
        float4 c = p4[idx];
        sx = c.x; sy = c.y; sz = c.z;
        if (tid == 0) {
            float* ow = out_xyz + ((size_t)bt * NS + i) * 3;
            ow[0] = sx; ow[1] = sy; ow[2] = sz;
        }
        r = rn;
    }
}

// ===================== FPS ablation: 4 waves =====================
// Same structure/semantics as fps_kernel but 256 threads x 32 pts and
// 4096 iterations (2x, so it ranks in top-5 even if faster per-iter).
// Output goes to workspace scratch only. Tests: does halving wave count
// cut the per-iteration sync cost (barrier skew, 4 vs 8 atomic partials)?
__global__ __launch_bounds__(256)
void fps_abl_4wave(const float* __restrict__ pts,
                   float* __restrict__ scratch)
{
#pragma clang fp contract(off)
    const int bt  = blockIdx.x;
    const int tid = threadIdx.x;
    const float* frame = pts + (size_t)bt * NPTS * 6;

    __shared__ float4 p4[NPTS];        // 128 KB
    __shared__ u64 ring[3];

    f32x2 x2[16], y2[16], z2[16], dd2[16];
#pragma unroll
    for (int j = 0; j < 32; ++j) {
        int n = j * 256 + tid;
        float x = frame[n*6+0], y = frame[n*6+1], z = frame[n*6+2];
        x2[j >> 1][j & 1] = x;
        y2[j >> 1][j & 1] = y;
        z2[j >> 1][j & 1] = z;
        dd2[j >> 1][j & 1] = 3.4028234663852886e38f;
        p4[n] = make_float4(x, y, z, 0.0f);
    }
    if (tid < 3) ring[tid] = 0;
    __syncthreads();
    float sx = p4[0].x, sy = p4[0].y, sz = p4[0].z;

    int r = 1;
    for (int i = 1; i < 4096; ++i) {
        f32x2 sxv = {sx, sx}, syv = {sy, sy}, szv = {sz, sz};
        f32x2 m2 = {0.0f, 0.0f};
#pragma unroll
        for (int q = 0; q < 16; ++q) {
            f32x2 dx = x2[q] - sxv;
            f32x2 dy = y2[q] - syv;
            f32x2 dz = z2[q] - szv;
            f32x2 dd = (dx*dx + dy*dy) + dz*dz;
            f32x2 nd;
            nd[0] = fminf(dd2[q][0], dd[0]);
            nd[1] = fminf(dd2[q][1], dd[1]);
            dd2[q] = nd;
            m2[0] = fmaxf(m2[0], nd[0]);
            m2[1] = fmaxf(m2[1], nd[1]);
        }
        float mloc = fmaxf(m2[0], m2[1]);
        int bestn = 0;
#pragma unroll
        for (int j = 31; j >= 0; --j)
            bestn = (dd2[j >> 1][j & 1] == mloc) ? (j * 256 + tid) : bestn;
        u64 key = ((u64)__float_as_uint(mloc) << 32) | (unsigned)(8191 - bestn);
#pragma unroll
        for (int off = 32; off > 0; off >>= 1) {
            u64 o = __shfl_xor(key, off, 64);
            key = (o > key) ? o : key;
        }
        if ((tid & 63) == 0) atomicMax(&ring[r], key);
        int rn = r + 1; if (rn == 3) rn = 0;
        if (tid == 0) ring[rn] = 0;
        __syncthreads();
        u64 k = ring[r];
        int idx = 8191 - (int)(k & 0xFFFFFFFFu);
        float4 c = p4[idx];
        sx = c.x; sy = c.y; sz = c.z;
        if (tid == 0) {
            float* ow = scratch + ((size_t)bt * 4096 + i) * 3;
            ow[0] = sx; ow[1] = sy; ow[2] = sz;
        }
        r = rn;
    }
}

// ============================ KNN =============================
// (unchanged from R9: 2 waves/block, per-wave halves, bitonic-lower-half
// exact merge; tie semantics == jax top_k.)
__device__ __forceinline__ void knn_compact(u64* st, int lane, int& cnt, float& rk_f)
{
    for (int e = 0; e < 32; ++e)
        if (e >= cnt) st[(e + 32) * 64 + lane] = ~0ull;
    for (int k = 2; k <= 32; k <<= 1)
        for (int j = k >> 1; j > 0; j >>= 1)
            for (int i = 0; i < 32; ++i) {
                int l = i ^ j;
                if (l > i) {
                    u64 a = st[(i + 32) * 64 + lane];
                    u64 b = st[(l + 32) * 64 + lane];
                    bool asc = ((i & k) == 0);
                    if ((a > b) == asc) {
                        st[(i + 32) * 64 + lane] = b;
                        st[(l + 32) * 64 + lane] = a;
                    }
                }
            }
    for (int i = 0; i < 32; ++i) {
        u64 a = st[i * 64 + lane];
        u64 b = st[(63 - i) * 64 + lane];
        if (b < a) st[i * 64 + lane] = b;
    }
    for (int j = 16; j > 0; j >>= 1)
        for (int i = 0; i < 32; ++i) {
            int l = i ^ j;
            if (l > i) {
                u64 a = st[i * 64 + lane];
                u64 b = st[l * 64 + lane];
                if (a > b) {
                    st[i * 64 + lane] = b;
                    st[l * 64 + lane] = a;
                }
            }
        }
    rk_f = __uint_as_float((unsigned)(st[31 * 64 + lane] >> 32));
    cnt = 0;
}

__global__ __launch_bounds__(128)
void knn_kernel(const float* __restrict__ pts,
                const float* __restrict__ anchors,
                unsigned short* __restrict__ knn_out)
{
    const int blk  = blockIdx.x;
    const int bt   = blk / 96;
    const int rr   = blk % 96;
    const int di   = rr / 32;
    const int sblk = rr % 32;
    const int b = bt >> 2, t0 = bt & 3;
    int lnb = t0 + di - 1; lnb = lnb < 0 ? 0 : (lnb > 3 ? 3 : lnb);
    const float* nb = pts + (size_t)(b * 4 + lnb) * NPTS * 6;
    const int tid  = threadIdx.x;
    const int w    = tid >> 6;
    const int lane = tid & 63;
    const int s    = sblk * 64 + lane;

    const float* ap = anchors + ((size_t)bt * NS + s) * 3;
    float ax = ap[0], ay = ap[1], az = ap[2];

    __shared__ u64 st[2][64 * 64];
    __shared__ u64 trash[64];
    __shared__ float4 tile[2][256];
    u64* stw = st[w];

    for (int e = 0; e < 64; ++e) stw[e * 64 + lane] = ~0ull;
    float rk_f = __uint_as_float(0xFFFFFFFFu);
    int cnt = 0;

    const int cbase = w * 4096;
    for (int tb = 0; tb < 16; ++tb) {
        __syncthreads();
#pragma unroll
        for (int q = 0; q < 4; ++q) {
            int c = q * 64 + lane;
            int n = cbase + tb * 256 + c;
            tile[w][c] = make_float4(nb[n*6+0], nb[n*6+1], nb[n*6+2], 0.0f);
        }
        __syncthreads();
        for (int c0 = 0; c0 < 256; c0 += 8) {
#pragma unroll
            for (int j = 0; j < 8; ++j) {
                float4 qv = tile[w][c0 + j];
                float dx = __fsub_rn(ax, qv.x);
                float dy = __fsub_rn(ay, qv.y);
                float dz = __fsub_rn(az, qv.z);
                float d2 = __fadd_rn(__fadd_rn(__fmul_rn(dx,dx), __fmul_rn(dy,dy)),
                                     __fmul_rn(dz,dz));
                u64 key = ((u64)__float_as_uint(d2) << 32)
                        | (unsigned)(cbase + tb * 256 + c0 + j);
                bool p = !(d2 > rk_f);
                u64* dst = p ? &stw[(32 + cnt) * 64 + lane] : &trash[lane];
                *dst = key;
                cnt += p ? 1 : 0;
            }
            if (__any(cnt >= 24)) knn_compact(stw, lane, cnt, rk_f);
        }
    }
    knn_compact(stw, lane, cnt, rk_f);
    __syncthreads();

    if (w == 0) {
        unsigned short* op = knn_out + (((size_t)bt * 3 + di) * NS + s) * KNNK;
#pragma unroll
        for (int e = 0; e < 32; ++e) {
            u64 a = st[0][e * 64 + lane];
            u64 c = st[1][(31 - e) * 64 + lane];
            u64 m = c < a ? c : a;
            op[e] = (unsigned short)(m & 0xFFFFull);
        }
    }
}

// ============================ MLP =============================
// (unchanged from R9: 4 anchors/block, 8p x 8k register tile)
__global__ __launch_bounds__(256)
void mlp_kernel(const float* __restrict__ pts,
                const float* __restrict__ anchors,
                const unsigned short* __restrict__ knn,
                const float* __restrict__ Wd,
                const float* __restrict__ Wm,
                float* __restrict__ out_feats)
{
    const int blk = blockIdx.x;
    const int bt  = blk >> 9;
    const int sq  = blk & 511;
    const int b = bt >> 2, t0 = bt & 3;
    const int tid = threadIdx.x;
    const int a   = tid >> 6;
    const int r   = tid & 63;
    const int p0  = (r & 15) * 8;
    const int kt  = r >> 4;
    const int k0  = kt * 8;
    const int s   = sq * 4 + a;

    __shared__ float WmT[64 * 128];
    __shared__ float Wds[256];
    __shared__ float h1[4][64][32];
    __shared__ float d4s[4][32][4];
    __shared__ float pmax[4][4][128];

    for (int i = tid; i < 8192; i += 256) {
        int pp = i >> 6, oo = i & 63;
        WmT[oo * 128 + pp] = Wm[i];
    }
    Wds[tid] = Wd[tid];

    float fsum0 = 0.0f, fsum1 = 0.0f;

    for (int dd = 0; dd < 3; ++dd) {
        __syncthreads();
        if (tid < 128) {
            int sa = tid >> 5, k = tid & 31;
            int ss = sq * 4 + sa;
            int lnb = t0 + dd - 1; lnb = lnb < 0 ? 0 : (lnb > 3 ? 3 : lnb);
            const float* nbf = pts + (size_t)(b*4 + lnb) * NPTS * 6;
            const float* ap = anchors + ((size_t)bt * NS + ss) * 3;
            int idx = knn[(((size_t)bt*3 + dd) * NS + ss) * KNNK + k];
            d4s[sa][k][0] = nbf[idx*6+0] - ap[0];
            d4s[sa][k][1] = nbf[idx*6+1] - ap[1];
            d4s[sa][k][2] = nbf[idx*6+2] - ap[2];
            d4s[sa][k][3] = (float)(dd - 1);
        }
        __syncthreads();
        {
            int k  = r & 31;
            int oh = r >> 5;
            float4 dv = *(const float4*)&d4s[a][k][0];
#pragma unroll
            for (int ii = 0; ii < 32; ++ii) {
                int o = oh * 32 + ii;
                float4 wv = *(const float4*)&Wds[o * 4];
                float h = fmaf(dv.x, wv.x, fmaf(dv.y, wv.y,
                             fmaf(dv.z, wv.z, dv.w * wv.w)));
                h1[a][o][k] = fmaxf(h, 0.0f);
            }
        }
        __syncthreads();
        float acc[8][8];
#pragma unroll
        for (int i = 0; i < 8; ++i)
#pragma unroll
            for (int j = 0; j < 8; ++j) acc[i][j] = 0.0f;
        for (int o = 0; o < 64; ++o) {
            float4 wv0 = *(const float4*)&WmT[o * 128 + p0];
            float4 wv1 = *(const float4*)&WmT[o * 128 + p0 + 4];
            float4 h0 = *(const float4*)&h1[a][o][k0];
            float4 h4 = *(const float4*)&h1[a][o][k0 + 4];
            float hw[8] = {h0.x, h0.y, h0.z, h0.w, h4.x, h4.y, h4.z, h4.w};
#pragma unroll
            for (int i = 0; i < 8; ++i) {
                float ww = (i < 4) ? ((i == 0) ? wv0.x : (i == 1) ? wv0.y :
                                      (i == 2) ? wv0.z : wv0.w)
                                   : ((i == 4) ? wv1.x : (i == 5) ? wv1.y :
                                      (i == 6) ? wv1.z : wv1.w);
#pragma unroll
                for (int j = 0; j < 8; ++j)
                    acc[i][j] = fmaf(ww, hw[j], acc[i][j]);
            }
        }
        float4 pmA, pmB;
#pragma unroll
        for (int i = 0; i < 8; ++i) {
            float m = acc[i][0];
#pragma unroll
            for (int j = 1; j < 8; ++j) m = fmaxf(m, acc[i][j]);
            if (i < 4) ((float*)&pmA)[i] = m;
            else       ((float*)&pmB)[i - 4] = m;
        }
        *(float4*)&pmax[a][kt][p0]     = pmA;
        *(float4*)&pmax[a][kt][p0 + 4] = pmB;
        __syncthreads();
        float m0 = fmaxf(fmaxf(pmax[a][0][r], pmax[a][1][r]),
                         fmaxf(pmax[a][2][r], pmax[a][3][r]));
        float m1 = fmaxf(fmaxf(pmax[a][0][r + 64], pmax[a][1][r + 64]),
                         fmaxf(pmax[a][2][r + 64], pmax[a][3][r + 64]));
        fsum0 += fmaxf(m0, 0.0f);
        fsum1 += fmaxf(m1, 0.0f);
    }
    out_feats[((size_t)bt * 128 + r) * NS + s]        = fsum0;
    out_feats[((size_t)bt * 128 + r + 64) * NS + s]   = fsum1;
}

// ========================== launcher ==========================
extern "C" void kernel_launch(void* const* d_in, const int* in_sizes, int n_in,
                              void* d_out, int out_size, void* d_ws, size_t ws_size,
                              hipStream_t stream)
{
    const float* pts = (const float*)d_in[0];   // [2,4,8192,6]
    const float* Wd  = (const float*)d_in[1];   // [64,4]
    const float* Wm  = (const float*)d_in[2];   // [128,64]

    float* out_xyz   = (float*)d_out;                 // [2,4,2048,3] == anchors
    float* out_feats = out_xyz + 8 * NS * 3;          // [2,4,128,2048]

    unsigned short* knn = (unsigned short*)d_ws;      // 786432 B at offset 0

    fps_kernel<<<8, 512, 0, stream>>>(pts, out_xyz);
    knn_kernel<<<8 * 3 * 32, 128, 0, stream>>>(pts, out_xyz, knn);
    mlp_kernel<<<8 * (NS / 4), 256, 0, stream>>>(pts, out_xyz, knn, Wd, Wm, out_feats);

    // Within-run measurement dispatch (scratch-only output, dropped once
    // it has answered the 4-wave question). Needs ws >= 1 MiB + 393 KiB.
    if (ws_size >= (size_t)(2u << 20)) {
        float* abl = (float*)((char*)d_ws + (1u << 20));
        fps_abl_4wave<<<8, 256, 0, stream>>>(pts, abl);
    }
}

// Round 13
// 8074.741 us; speedup vs baseline: 1.0008x; 1.0008x over previous
//
#include <hip/hip_runtime.h>
#include <stdint.h>

#define NPTS 8192
#define NS   2048
#define KNNK 32

typedef unsigned long long u64;
typedef float f32x2 __attribute__((ext_vector_type(2)));

// ============================ FPS =============================
// R4's kernel VERBATIM — kept byte-identical as the within-run reference
// (cross-run clock variance is +-25-30%, so only same-run comparisons count).
__global__ __launch_bounds__(512)
void fps_kernel(const float* __restrict__ pts,
                float* __restrict__ out_xyz)
{
#pragma clang fp contract(off)
    const int bt  = blockIdx.x;        // b*4 + t0
    const int tid = threadIdx.x;
    const float* frame = pts + (size_t)bt * NPTS * 6;

    __shared__ float4 p4[NPTS];        // 128 KB coords copy
    __shared__ u64 ring[3];

    f32x2 x2[8], y2[8], z2[8], dd2[8];
#pragma unroll
    for (int j = 0; j < 16; ++j) {
        int n = j * 512 + tid;
        float x = frame[n*6+0], y = frame[n*6+1], z = frame[n*6+2];
        x2[j >> 1][j & 1] = x;
        y2[j >> 1][j & 1] = y;
        z2[j >> 1][j & 1] = z;
        dd2[j >> 1][j & 1] = 3.4028234663852886e38f;
        p4[n] = make_float4(x, y, z, 0.0f);
    }
    if (tid < 3) ring[tid] = 0;
    if (tid == 0) {                    // selection 0 = point 0
        float* ow = out_xyz + (size_t)bt * NS * 3;
        ow[0] = x2[0][0]; ow[1] = y2[0][0]; ow[2] = z2[0][0];
    }
    __syncthreads();
    float sx = p4[0].x, sy = p4[0].y, sz = p4[0].z;

    int r = 1;                         // ring slot for iteration i
    for (int i = 1; i < NS; ++i) {
        f32x2 sxv = {sx, sx}, syv = {sy, sy}, szv = {sz, sz};
        f32x2 m2 = {0.0f, 0.0f};
#pragma unroll
        for (int q = 0; q < 8; ++q) {
            f32x2 dx = x2[q] - sxv;
            f32x2 dy = y2[q] - syv;
            f32x2 dz = z2[q] - szv;
            f32x2 dd = (dx*dx + dy*dy) + dz*dz;
            f32x2 nd;
            nd[0] = fminf(dd2[q][0], dd[0]);
            nd[1] = fminf(dd2[q][1], dd[1]);
            dd2[q] = nd;
            m2[0] = fmaxf(m2[0], nd[0]);
            m2[1] = fmaxf(m2[1], nd[1]);
        }
        float mloc = fmaxf(m2[0], m2[1]);
        int bestn = 0;
#pragma unroll
        for (int j = 15; j >= 0; --j)
            bestn = (dd2[j >> 1][j & 1] == mloc) ? (j * 512 + tid) : bestn;
        u64 key = ((u64)__float_as_uint(mloc) << 32) | (unsigned)(8191 - bestn);
#pragma unroll
        for (int off = 32; off > 0; off >>= 1) {
            u64 o = __shfl_xor(key, off, 64);
            key = (o > key) ? o : key;
        }
        if ((tid & 63) == 0) atomicMax(&ring[r], key);
        int rn = r + 1; if (rn == 3) rn = 0;
        if (tid == 0) ring[rn] = 0;
        __syncthreads();
        u64 k = ring[r];
        int idx = 8191 - (int)(k & 0xFFFFFFFFu);
        float4 c = p4[idx];
        sx = c.x; sy = c.y; sz = c.z;
        if (tid == 0) {
            float* ow = out_xyz + ((size_t)bt * NS + i) * 3;
            ow[0] = sx; ow[1] = sy; ow[2] = sz;
        }
        r = rn;
    }
}

// ===================== FPS ablation: 4 waves =====================
// Same structure/semantics as fps_kernel but 256 threads x 32 pts and
// 4096 iterations (2x, so it ranks in top-5 even if faster per-iter).
// Output goes to workspace scratch only. Tests: does halving wave count
// cut the per-iteration sync cost (barrier skew, 4 vs 8 atomic partials)?
__global__ __launch_bounds__(256)
void fps_abl_4wave(const float* __restrict__ pts,
                   float* __restrict__ scratch)
{
#pragma clang fp contract(off)
    const int bt  = blockIdx.x;
    const int tid = threadIdx.x;
    const float* frame = pts + (size_t)bt * NPTS * 6;

    __shared__ float4 p4[NPTS];        // 128 KB
    __shared__ u64 ring[3];

    f32x2 x2[16], y2[16], z2[16], dd2[16];
#pragma unroll
    for (int j = 0; j < 32; ++j) {
        int n = j * 256 + tid;
        float x = frame[n*6+0], y = frame[n*6+1], z = frame[n*6+2];
        x2[j >> 1][j & 1] = x;
        y2[j >> 1][j & 1] = y;
        z2[j >> 1][j & 1] = z;
        dd2[j >> 1][j & 1] = 3.4028234663852886e38f;
        p4[n] = make_float4(x, y, z, 0.0f);
    }
    if (tid < 3) ring[tid] = 0;
    __syncthreads();
    float sx = p4[0].x, sy = p4[0].y, sz = p4[0].z;

    int r = 1;
    for (int i = 1; i < 4096; ++i) {
        f32x2 sxv = {sx, sx}, syv = {sy, sy}, szv = {sz, sz};
        f32x2 m2 = {0.0f, 0.0f};
#pragma unroll
        for (int q = 0; q < 16; ++q) {
            f32x2 dx = x2[q] - sxv;
            f32x2 dy = y2[q] - syv;
            f32x2 dz = z2[q] - szv;
            f32x2 dd = (dx*dx + dy*dy) + dz*dz;
            f32x2 nd;
            nd[0] = fminf(dd2[q][0], dd[0]);
            nd[1] = fminf(dd2[q][1], dd[1]);
            dd2[q] = nd;
            m2[0] = fmaxf(m2[0], nd[0]);
            m2[1] = fmaxf(m2[1], nd[1]);
        }
        float mloc = fmaxf(m2[0], m2[1]);
        int bestn = 0;
#pragma unroll
        for (int j = 31; j >= 0; --j)
            bestn = (dd2[j >> 1][j & 1] == mloc) ? (j * 256 + tid) : bestn;
        u64 key = ((u64)__float_as_uint(mloc) << 32) | (unsigned)(8191 - bestn);
#pragma unroll
        for (int off = 32; off > 0; off >>= 1) {
            u64 o = __shfl_xor(key, off, 64);
            key = (o > key) ? o : key;
        }
        if ((tid & 63) == 0) atomicMax(&ring[r], key);
        int rn = r + 1; if (rn == 3) rn = 0;
        if (tid == 0) ring[rn] = 0;
        __syncthreads();
        u64 k = ring[r];
        int idx = 8191 - (int)(k & 0xFFFFFFFFu);
        float4 c = p4[idx];
        sx = c.x; sy = c.y; sz = c.z;
        if (tid == 0) {
            float* ow = scratch + ((size_t)bt * 4096 + i) * 3;
            ow[0] = sx; ow[1] = sy; ow[2] = sz;
        }
        r = rn;
    }
}

// ============================ KNN =============================
// (unchanged from R9: 2 waves/block, per-wave halves, bitonic-lower-half
// exact merge; tie semantics == jax top_k.)
__device__ __forceinline__ void knn_compact(u64* st, int lane, int& cnt, float& rk_f)
{
    for (int e = 0; e < 32; ++e)
        if (e >= cnt) st[(e + 32) * 64 + lane] = ~0ull;
    for (int k = 2; k <= 32; k <<= 1)
        for (int j = k >> 1; j > 0; j >>= 1)
            for (int i = 0; i < 32; ++i) {
                int l = i ^ j;
                if (l > i) {
                    u64 a = st[(i + 32) * 64 + lane];
                    u64 b = st[(l + 32) * 64 + lane];
                    bool asc = ((i & k) == 0);
                    if ((a > b) == asc) {
                        st[(i + 32) * 64 + lane] = b;
                        st[(l + 32) * 64 + lane] = a;
                    }
                }
            }
    for (int i = 0; i < 32; ++i) {
        u64 a = st[i * 64 + lane];
        u64 b = st[(63 - i) * 64 + lane];
        if (b < a) st[i * 64 + lane] = b;
    }
    for (int j = 16; j > 0; j >>= 1)
        for (int i = 0; i < 32; ++i) {
            int l = i ^ j;
            if (l > i) {
                u64 a = st[i * 64 + lane];
                u64 b = st[l * 64 + lane];
                if (a > b) {
                    st[i * 64 + lane] = b;
                    st[l * 64 + lane] = a;
                }
            }
        }
    rk_f = __uint_as_float((unsigned)(st[31 * 64 + lane] >> 32));
    cnt = 0;
}

__global__ __launch_bounds__(128)
void knn_kernel(const float* __restrict__ pts,
                const float* __restrict__ anchors,
                unsigned short* __restrict__ knn_out)
{
    const int blk  = blockIdx.x;
    const int bt   = blk / 96;
    const int rr   = blk % 96;
    const int di   = rr / 32;
    const int sblk = rr % 32;
    const int b = bt >> 2, t0 = bt & 3;
    int lnb = t0 + di - 1; lnb = lnb < 0 ? 0 : (lnb > 3 ? 3 : lnb);
    const float* nb = pts + (size_t)(b * 4 + lnb) * NPTS * 6;
    const int tid  = threadIdx.x;
    const int w    = tid >> 6;
    const int lane = tid & 63;
    const int s    = sblk * 64 + lane;

    const float* ap = anchors + ((size_t)bt * NS + s) * 3;
    float ax = ap[0], ay = ap[1], az = ap[2];

    __shared__ u64 st[2][64 * 64];
    __shared__ u64 trash[64];
    __shared__ float4 tile[2][256];
    u64* stw = st[w];

    for (int e = 0; e < 64; ++e) stw[e * 64 + lane] = ~0ull;
    float rk_f = __uint_as_float(0xFFFFFFFFu);
    int cnt = 0;

    const int cbase = w * 4096;
    for (int tb = 0; tb < 16; ++tb) {
        __syncthreads();
#pragma unroll
        for (int q = 0; q < 4; ++q) {
            int c = q * 64 + lane;
            int n = cbase + tb * 256 + c;
            tile[w][c] = make_float4(nb[n*6+0], nb[n*6+1], nb[n*6+2], 0.0f);
        }
        __syncthreads();
        for (int c0 = 0; c0 < 256; c0 += 8) {
#pragma unroll
            for (int j = 0; j < 8; ++j) {
                float4 qv = tile[w][c0 + j];
                float dx = __fsub_rn(ax, qv.x);
                float dy = __fsub_rn(ay, qv.y);
                float dz = __fsub_rn(az, qv.z);
                float d2 = __fadd_rn(__fadd_rn(__fmul_rn(dx,dx), __fmul_rn(dy,dy)),
                                     __fmul_rn(dz,dz));
                u64 key = ((u64)__float_as_uint(d2) << 32)
                        | (unsigned)(cbase + tb * 256 + c0 + j);
                bool p = !(d2 > rk_f);
                u64* dst = p ? &stw[(32 + cnt) * 64 + lane] : &trash[lane];
                *dst = key;
                cnt += p ? 1 : 0;
            }
            if (__any(cnt >= 24)) knn_compact(stw, lane, cnt, rk_f);
        }
    }
    knn_compact(stw, lane, cnt, rk_f);
    __syncthreads();

    if (w == 0) {
        unsigned short* op = knn_out + (((size_t)bt * 3 + di) * NS + s) * KNNK;
#pragma unroll
        for (int e = 0; e < 32; ++e) {
            u64 a = st[0][e * 64 + lane];
            u64 c = st[1][(31 - e) * 64 + lane];
            u64 m = c < a ? c : a;
            op[e] = (unsigned short)(m & 0xFFFFull);
        }
    }
}

// ============================ MLP =============================
// (unchanged from R9: 4 anchors/block, 8p x 8k register tile)
__global__ __launch_bounds__(256)
void mlp_kernel(const float* __restrict__ pts,
                const float* __restrict__ anchors,
                const unsigned short* __restrict__ knn,
                const float* __restrict__ Wd,
                const float* __restrict__ Wm,
                float* __restrict__ out_feats)
{
    const int blk = blockIdx.x;
    const int bt  = blk >> 9;
    const int sq  = blk & 511;
    const int b = bt >> 2, t0 = bt & 3;
    const int tid = threadIdx.x;
    const int a   = tid >> 6;
    const int r   = tid & 63;
    const int p0  = (r & 15) * 8;
    const int kt  = r >> 4;
    const int k0  = kt * 8;
    const int s   = sq * 4 + a;

    __shared__ float WmT[64 * 128];
    __shared__ float Wds[256];
    __shared__ float h1[4][64][32];
    __shared__ float d4s[4][32][4];
    __shared__ float pmax[4][4][128];

    for (int i = tid; i < 8192; i += 256) {
        int pp = i >> 6, oo = i & 63;
        WmT[oo * 128 + pp] = Wm[i];
    }
    Wds[tid] = Wd[tid];

    float fsum0 = 0.0f, fsum1 = 0.0f;

    for (int dd = 0; dd < 3; ++dd) {
        __syncthreads();
        if (tid < 128) {
            int sa = tid >> 5, k = tid & 31;
            int ss = sq * 4 + sa;
            int lnb = t0 + dd - 1; lnb = lnb < 0 ? 0 : (lnb > 3 ? 3 : lnb);
            const float* nbf = pts + (size_t)(b*4 + lnb) * NPTS * 6;
            const float* ap = anchors + ((size_t)bt * NS + ss) * 3;
            int idx = knn[(((size_t)bt*3 + dd) * NS + ss) * KNNK + k];
            d4s[sa][k][0] = nbf[idx*6+0] - ap[0];
            d4s[sa][k][1] = nbf[idx*6+1] - ap[1];
            d4s[sa][k][2] = nbf[idx*6+2] - ap[2];
            d4s[sa][k][3] = (float)(dd - 1);
        }
        __syncthreads();
        {
            int k  = r & 31;
            int oh = r >> 5;
            float4 dv = *(const float4*)&d4s[a][k][0];
#pragma unroll
            for (int ii = 0; ii < 32; ++ii) {
                int o = oh * 32 + ii;
                float4 wv = *(const float4*)&Wds[o * 4];
                float h = fmaf(dv.x, wv.x, fmaf(dv.y, wv.y,
                             fmaf(dv.z, wv.z, dv.w * wv.w)));
                h1[a][o][k] = fmaxf(h, 0.0f);
            }
        }
        __syncthreads();
        float acc[8][8];
#pragma unroll
        for (int i = 0; i < 8; ++i)
#pragma unroll
            for (int j = 0; j < 8; ++j) acc[i][j] = 0.0f;
        for (int o = 0; o < 64; ++o) {
            float4 wv0 = *(const float4*)&WmT[o * 128 + p0];
            float4 wv1 = *(const float4*)&WmT[o * 128 + p0 + 4];
            float4 h0 = *(const float4*)&h1[a][o][k0];
            float4 h4 = *(const float4*)&h1[a][o][k0 + 4];
            float hw[8] = {h0.x, h0.y, h0.z, h0.w, h4.x, h4.y, h4.z, h4.w};
#pragma unroll
            for (int i = 0; i < 8; ++i) {
                float ww = (i < 4) ? ((i == 0) ? wv0.x : (i == 1) ? wv0.y :
                                      (i == 2) ? wv0.z : wv0.w)
                                   : ((i == 4) ? wv1.x : (i == 5) ? wv1.y :
                                      (i == 6) ? wv1.z : wv1.w);
#pragma unroll
                for (int j = 0; j < 8; ++j)
                    acc[i][j] = fmaf(ww, hw[j], acc[i][j]);
            }
        }
        float4 pmA, pmB;
#pragma unroll
        for (int i = 0; i < 8; ++i) {
            float m = acc[i][0];
#pragma unroll
            for (int j = 1; j < 8; ++j) m = fmaxf(m, acc[i][j]);
            if (i < 4) ((float*)&pmA)[i] = m;
            else       ((float*)&pmB)[i - 4] = m;
        }
        *(float4*)&pmax[a][kt][p0]     = pmA;
        *(float4*)&pmax[a][kt][p0 + 4] = pmB;
        __syncthreads();
        float m0 = fmaxf(fmaxf(pmax[a][0][r], pmax[a][1][r]),
                         fmaxf(pmax[a][2][r], pmax[a][3][r]));
        float m1 = fmaxf(fmaxf(pmax[a][0][r + 64], pmax[a][1][r + 64]),
                         fmaxf(pmax[a][2][r + 64], pmax[a][3][r + 64]));
        fsum0 += fmaxf(m0, 0.0f);
        fsum1 += fmaxf(m1, 0.0f);
    }
    out_feats[((size_t)bt * 128 + r) * NS + s]        = fsum0;
    out_feats[((size_t)bt * 128 + r + 64) * NS + s]   = fsum1;
}

// ========================== launcher ==========================
extern "C" void kernel_launch(void* const* d_in, const int* in_sizes, int n_in,
                              void* d_out, int out_size, void* d_ws, size_t ws_size,
                              hipStream_t stream)
{
    const float* pts = (const float*)d_in[0];   // [2,4,8192,6]
    const float* Wd  = (const float*)d_in[1];   // [64,4]
    const float* Wm  = (const float*)d_in[2];   // [128,64]

    float* out_xyz   = (float*)d_out;                 // [2,4,2048,3] == anchors
    float* out_feats = out_xyz + 8 * NS * 3;          // [2,4,128,2048]

    unsigned short* knn = (unsigned short*)d_ws;      // 786432 B at offset 0

    fps_kernel<<<8, 512, 0, stream>>>(pts, out_xyz);
    knn_kernel<<<8 * 3 * 32, 128, 0, stream>>>(pts, out_xyz, knn);
    mlp_kernel<<<8 * (NS / 4), 256, 0, stream>>>(pts, out_xyz, knn, Wd, Wm, out_feats);

    // Within-run measurement dispatch (scratch-only output, dropped once
    // it has answered the 4-wave question). Needs ws >= 1 MiB + 393 KiB.
    if (ws_size >= (size_t)(2u << 20)) {
        float* abl = (float*)((char*)d_ws + (1u << 20));
        fps_abl_4wave<<<8, 256, 0, stream>>>(pts, abl);
    }
}

// Round 14
// 2974.079 us; speedup vs baseline: 2.7171x; 2.7150x over previous
//
#include <hip/hip_runtime.h>
#include <stdint.h>

#define NPTS 8192
#define NS   2048
#define KNNK 32

typedef unsigned long long u64;
typedef float f32x2 __attribute__((ext_vector_type(2)));

// ============================ FPS =============================
// R4's kernel VERBATIM — parked at its empirical floor (~0.9 us/iter).
// R13 ablation: 4-wave variant = 1096 ns/iter vs this 8-wave ~930 ns/iter
// (same-run A/B) -> wave count ruled out as the lever.
__global__ __launch_bounds__(512)
void fps_kernel(const float* __restrict__ pts,
                float* __restrict__ out_xyz)
{
#pragma clang fp contract(off)
    const int bt  = blockIdx.x;        // b*4 + t0
    const int tid = threadIdx.x;
    const float* frame = pts + (size_t)bt * NPTS * 6;

    __shared__ float4 p4[NPTS];        // 128 KB coords copy
    __shared__ u64 ring[3];

    f32x2 x2[8], y2[8], z2[8], dd2[8];
#pragma unroll
    for (int j = 0; j < 16; ++j) {
        int n = j * 512 + tid;
        float x = frame[n*6+0], y = frame[n*6+1], z = frame[n*6+2];
        x2[j >> 1][j & 1] = x;
        y2[j >> 1][j & 1] = y;
        z2[j >> 1][j & 1] = z;
        dd2[j >> 1][j & 1] = 3.4028234663852886e38f;
        p4[n] = make_float4(x, y, z, 0.0f);
    }
    if (tid < 3) ring[tid] = 0;
    if (tid == 0) {                    // selection 0 = point 0
        float* ow = out_xyz + (size_t)bt * NS * 3;
        ow[0] = x2[0][0]; ow[1] = y2[0][0]; ow[2] = z2[0][0];
    }
    __syncthreads();
    float sx = p4[0].x, sy = p4[0].y, sz = p4[0].z;

    int r = 1;                         // ring slot for iteration i
    for (int i = 1; i < NS; ++i) {
        f32x2 sxv = {sx, sx}, syv = {sy, sy}, szv = {sz, sz};
        f32x2 m2 = {0.0f, 0.0f};
#pragma unroll
        for (int q = 0; q < 8; ++q) {
            f32x2 dx = x2[q] - sxv;
            f32x2 dy = y2[q] - syv;
            f32x2 dz = z2[q] - szv;
            f32x2 dd = (dx*dx + dy*dy) + dz*dz;
            f32x2 nd;
            nd[0] = fminf(dd2[q][0], dd[0]);
            nd[1] = fminf(dd2[q][1], dd[1]);
            dd2[q] = nd;
            m2[0] = fmaxf(m2[0], nd[0]);
            m2[1] = fmaxf(m2[1], nd[1]);
        }
        float mloc = fmaxf(m2[0], m2[1]);
        int bestn = 0;
#pragma unroll
        for (int j = 15; j >= 0; --j)
            bestn = (dd2[j >> 1][j & 1] == mloc) ? (j * 512 + tid) : bestn;
        u64 key = ((u64)__float_as_uint(mloc) << 32) | (unsigned)(8191 - bestn);
#pragma unroll
        for (int off = 32; off > 0; off >>= 1) {
            u64 o = __shfl_xor(key, off, 64);
            key = (o > key) ? o : key;
        }
        if ((tid & 63) == 0) atomicMax(&ring[r], key);
        int rn = r + 1; if (rn == 3) rn = 0;
        if (tid == 0) ring[rn] = 0;
        __syncthreads();
        u64 k = ring[r];
        int idx = 8191 - (int)(k & 0xFFFFFFFFu);
        float4 c = p4[idx];
        sx = c.x; sy = c.y; sz = c.z;
        if (tid == 0) {
            float* ow = out_xyz + ((size_t)bt * NS + i) * 3;
            ow[0] = sx; ow[1] = sy; ow[2] = sz;
        }
        r = rn;
    }
}

// ============================ KNN =============================
// Register-resident top-32: per-lane main[32] u64 lives in VGPRs; the
// bitonic compaction network (static indexing) runs entirely in registers
// -> off the shared LDS pipe (the old in-LDS sort was ~11.5K LDS-cy per
// compaction and dominated KNN). LDS keeps only: SoA candidate tiles
// (tx/ty/tz, broadcast b128 reads = 4 candidates per 3 ops) and the
// dynamic-index append buffer (33 rows x 64 lanes; row 32 = trash).
// Semantics unchanged vs R6/R9 (passed): u64 keys (d2bits<<32|idx),
// insert test !(d2 > rk_f) (NaN-safe, boundary ties evicted by full-u64
// compaction -> exact set), capacity 32 / check-every-4 at >=28,
// cross-wave bitonic-lower-half merge = exact union top-32 set,
// tie semantics == jax top_k.
__device__ __forceinline__ void knn_compact_reg(u64 (&mn)[32], const u64* bufLDS,
                                                int lane, int& cnt, float& rk_f)
{
    u64 b[32];
#pragma unroll
    for (int e = 0; e < 32; ++e) {
        u64 v = bufLDS[e * 64 + lane];
        b[e] = (e < cnt) ? v : ~0ull;
    }
    // bitonic sort b[] ascending (identical network to the proven LDS one)
#pragma unroll
    for (int k = 2; k <= 32; k <<= 1) {
#pragma unroll
        for (int j = k >> 1; j > 0; j >>= 1) {
#pragma unroll
            for (int i = 0; i < 32; ++i) {
                int l = i ^ j;
                if (l > i) {
                    bool asc = ((i & k) == 0);
                    u64 x = b[i], y = b[l];
                    if ((x > y) == asc) { b[i] = y; b[l] = x; }
                }
            }
        }
    }
    // merge: mn[i] vs b[31-i], keep mins (bitonic lower half)
#pragma unroll
    for (int i = 0; i < 32; ++i) {
        u64 y = b[31 - i];
        if (y < mn[i]) mn[i] = y;
    }
    // re-sort bitonic mn[] ascending: 5 merge stages
#pragma unroll
    for (int j = 16; j > 0; j >>= 1) {
#pragma unroll
        for (int i = 0; i < 32; ++i) {
            int l = i ^ j;
            if (l > i) {
                u64 x = mn[i], y = mn[l];
                if (x > y) { mn[i] = y; mn[l] = x; }
            }
        }
    }
    rk_f = __uint_as_float((unsigned)(mn[31] >> 32));
    cnt = 0;
}

__global__ __launch_bounds__(128)
void knn_kernel(const float* __restrict__ pts,
                const float* __restrict__ anchors,
                unsigned short* __restrict__ knn_out)
{
    const int blk  = blockIdx.x;       // 8bt * 3di * 32 sblk
    const int bt   = blk / 96;
    const int rr   = blk % 96;
    const int di   = rr / 32;
    const int sblk = rr % 32;
    const int b = bt >> 2, t0 = bt & 3;
    int lnb = t0 + di - 1; lnb = lnb < 0 ? 0 : (lnb > 3 ? 3 : lnb);
    const float* nb = pts + (size_t)(b * 4 + lnb) * NPTS * 6;
    const int tid  = threadIdx.x;
    const int w    = tid >> 6;         // wave: candidate half owner
    const int lane = tid & 63;
    const int s    = sblk * 64 + lane;

    const float* ap = anchors + ((size_t)bt * NS + s) * 3;
    float ax = ap[0], ay = ap[1], az = ap[2];

    __shared__ __align__(16) float tx[2][256];   // SoA tiles, 6 KB
    __shared__ __align__(16) float ty[2][256];
    __shared__ __align__(16) float tz[2][256];
    __shared__ u64 buf[2][33][64];               // append + trash, 33.75 KB

    u64 mn[32];
#pragma unroll
    for (int e = 0; e < 32; ++e) mn[e] = ~0ull;
    float rk_f = __uint_as_float(0xFFFFFFFFu);   // NaN -> always insert
    int cnt = 0;

    const int cbase = w * 4096;
    for (int tb = 0; tb < 16; ++tb) {
        __syncthreads();
#pragma unroll
        for (int q = 0; q < 4; ++q) {
            int c = q * 64 + lane;
            int n = cbase + tb * 256 + c;
            tx[w][c] = nb[n*6+0];
            ty[w][c] = nb[n*6+1];
            tz[w][c] = nb[n*6+2];
        }
        __syncthreads();
        for (int g = 0; g < 64; ++g) {           // 4 candidates per g
            float4 xs = ((const float4*)&tx[w][0])[g];
            float4 ys = ((const float4*)&ty[w][0])[g];
            float4 zs = ((const float4*)&tz[w][0])[g];
            int n0 = cbase + tb * 256 + g * 4;
#pragma unroll
            for (int jj = 0; jj < 4; ++jj) {
                float qx = jj==0?xs.x:jj==1?xs.y:jj==2?xs.z:xs.w;
                float qy = jj==0?ys.x:jj==1?ys.y:jj==2?ys.z:ys.w;
                float qz = jj==0?zs.x:jj==1?zs.y:jj==2?zs.z:zs.w;
                float dx = __fsub_rn(ax, qx);
                float dy = __fsub_rn(ay, qy);
                float dz = __fsub_rn(az, qz);
                float d2 = __fadd_rn(__fadd_rn(__fmul_rn(dx,dx), __fmul_rn(dy,dy)),
                                     __fmul_rn(dz,dz));
                bool p = !(d2 > rk_f);
                int row = p ? cnt : 32;          // losers -> trash row
                buf[w][row][lane] = ((u64)__float_as_uint(d2) << 32)
                                  | (unsigned)(n0 + jj);
                cnt += p ? 1 : 0;
            }
            // post-g cnt <= 27+4 = 31 <= capacity
            if (__any(cnt >= 28))
                knn_compact_reg(mn, &buf[w][0][0], lane, cnt, rk_f);
        }
    }
    knn_compact_reg(mn, &buf[w][0][0], lane, cnt, rk_f);
    __syncthreads();
    if (w == 1) {
#pragma unroll
        for (int e = 0; e < 32; ++e) buf[1][e][lane] = mn[e];
    }
    __syncthreads();
    if (w == 0) {
        unsigned short* op = knn_out + (((size_t)bt * 3 + di) * NS + s) * KNNK;
#pragma unroll
        for (int e = 0; e < 32; ++e) {
            u64 c = buf[1][31 - e][lane];
            u64 m = c < mn[e] ? c : mn[e];       // lower half of bitonic 64-seq
            op[e] = (unsigned short)(m & 0xFFFFull);
        }
    }
}

// ============================ MLP =============================
// (unchanged from R9: 4 anchors/block, 8p x 8k register tile)
__global__ __launch_bounds__(256)
void mlp_kernel(const float* __restrict__ pts,
                const float* __restrict__ anchors,
                const unsigned short* __restrict__ knn,
                const float* __restrict__ Wd,
                const float* __restrict__ Wm,
                float* __restrict__ out_feats)
{
    const int blk = blockIdx.x;
    const int bt  = blk >> 9;
    const int sq  = blk & 511;
    const int b = bt >> 2, t0 = bt & 3;
    const int tid = threadIdx.x;
    const int a   = tid >> 6;
    const int r   = tid & 63;
    const int p0  = (r & 15) * 8;
    const int kt  = r >> 4;
    const int k0  = kt * 8;
    const int s   = sq * 4 + a;

    __shared__ float WmT[64 * 128];
    __shared__ float Wds[256];
    __shared__ float h1[4][64][32];
    __shared__ float d4s[4][32][4];
    __shared__ float pmax[4][4][128];

    for (int i = tid; i < 8192; i += 256) {
        int pp = i >> 6, oo = i & 63;
        WmT[oo * 128 + pp] = Wm[i];
    }
    Wds[tid] = Wd[tid];

    float fsum0 = 0.0f, fsum1 = 0.0f;

    for (int dd = 0; dd < 3; ++dd) {
        __syncthreads();
        if (tid < 128) {
            int sa = tid >> 5, k = tid & 31;
            int ss = sq * 4 + sa;
            int lnb = t0 + dd - 1; lnb = lnb < 0 ? 0 : (lnb > 3 ? 3 : lnb);
            const float* nbf = pts + (size_t)(b*4 + lnb) * NPTS * 6;
            const float* ap = anchors + ((size_t)bt * NS + ss) * 3;
            int idx = knn[(((size_t)bt*3 + dd) * NS + ss) * KNNK + k];
            d4s[sa][k][0] = nbf[idx*6+0] - ap[0];
            d4s[sa][k][1] = nbf[idx*6+1] - ap[1];
            d4s[sa][k][2] = nbf[idx*6+2] - ap[2];
            d4s[sa][k][3] = (float)(dd - 1);
        }
        __syncthreads();
        {
            int k  = r & 31;
            int oh = r >> 5;
            float4 dv = *(const float4*)&d4s[a][k][0];
#pragma unroll
            for (int ii = 0; ii < 32; ++ii) {
                int o = oh * 32 + ii;
                float4 wv = *(const float4*)&Wds[o * 4];
                float h = fmaf(dv.x, wv.x, fmaf(dv.y, wv.y,
                             fmaf(dv.z, wv.z, dv.w * wv.w)));
                h1[a][o][k] = fmaxf(h, 0.0f);
            }
        }
        __syncthreads();
        float acc[8][8];
#pragma unroll
        for (int i = 0; i < 8; ++i)
#pragma unroll
            for (int j = 0; j < 8; ++j) acc[i][j] = 0.0f;
        for (int o = 0; o < 64; ++o) {
            float4 wv0 = *(const float4*)&WmT[o * 128 + p0];
            float4 wv1 = *(const float4*)&WmT[o * 128 + p0 + 4];
            float4 h0 = *(const float4*)&h1[a][o][k0];
            float4 h4 = *(const float4*)&h1[a][o][k0 + 4];
            float hw[8] = {h0.x, h0.y, h0.z, h0.w, h4.x, h4.y, h4.z, h4.w};
#pragma unroll
            for (int i = 0; i < 8; ++i) {
                float ww = (i < 4) ? ((i == 0) ? wv0.x : (i == 1) ? wv0.y :
                                      (i == 2) ? wv0.z : wv0.w)
                                   : ((i == 4) ? wv1.x : (i == 5) ? wv1.y :
                                      (i == 6) ? wv1.z : wv1.w);
#pragma unroll
                for (int j = 0; j < 8; ++j)
                    acc[i][j] = fmaf(ww, hw[j], acc[i][j]);
            }
        }
        float4 pmA, pmB;
#pragma unroll
        for (int i = 0; i < 8; ++i) {
            float m = acc[i][0];
#pragma unroll
            for (int j = 1; j < 8; ++j) m = fmaxf(m, acc[i][j]);
            if (i < 4) ((float*)&pmA)[i] = m;
            else       ((float*)&pmB)[i - 4] = m;
        }
        *(float4*)&pmax[a][kt][p0]     = pmA;
        *(float4*)&pmax[a][kt][p0 + 4] = pmB;
        __syncthreads();
        float m0 = fmaxf(fmaxf(pmax[a][0][r], pmax[a][1][r]),
                         fmaxf(pmax[a][2][r], pmax[a][3][r]));
        float m1 = fmaxf(fmaxf(pmax[a][0][r + 64], pmax[a][1][r + 64]),
                         fmaxf(pmax[a][2][r + 64], pmax[a][3][r + 64]));
        fsum0 += fmaxf(m0, 0.0f);
        fsum1 += fmaxf(m1, 0.0f);
    }
    out_feats[((size_t)bt * 128 + r) * NS + s]        = fsum0;
    out_feats[((size_t)bt * 128 + r + 64) * NS + s]   = fsum1;
}

// ========================== launcher ==========================
extern "C" void kernel_launch(void* const* d_in, const int* in_sizes, int n_in,
                              void* d_out, int out_size, void* d_ws, size_t ws_size,
                              hipStream_t stream)
{
    const float* pts = (const float*)d_in[0];   // [2,4,8192,6]
    const float* Wd  = (const float*)d_in[1];   // [64,4]
    const float* Wm  = (const float*)d_in[2];   // [128,64]

    float* out_xyz   = (float*)d_out;                 // [2,4,2048,3] == anchors
    float* out_feats = out_xyz + 8 * NS * 3;          // [2,4,128,2048]

    unsigned short* knn = (unsigned short*)d_ws;      // 8*3*2048*32 u16

    fps_kernel<<<8, 512, 0, stream>>>(pts, out_xyz);
    knn_kernel<<<8 * 3 * 32, 128, 0, stream>>>(pts, out_xyz, knn);
    mlp_kernel<<<8 * (NS / 4), 256, 0, stream>>>(pts, out_xyz, knn, Wd, Wm, out_feats);
}